// Round 10
// baseline (209.564 us; speedup 1.0000x reference)
//
#include <hip/hip_runtime.h>

#define CLA_NATOMS 8192
#define CLA_NSHIFT 14
#define CLA_NROWS (CLA_NSHIFT * CLA_NATOMS)  // 114688 rows = (k, i)
#define CLA_NTILE 112                        // scan tiles of 1024 rows
#define CLA_NCELL 512                        // 8x8x8 spatial bins
#define CLA_CAP 128                          // max hits per row (mean 2, k=0 max ~90)
#define CLA_C2 ((float)(5.2 * 5.2))          // f32 compare (JAX weak promotion)
#define CLA_R 5.35f                          // candidate interval half-width

__device__ const int cla_shifts[CLA_NSHIFT][3] = {
    {0, 0, 0},
    {-1, 0, 0}, {-1, -1, 0}, {0, -1, 0}, {1, -1, 0},
    {-1, 1, -1}, {0, 1, -1}, {1, 1, -1}, {-1, 0, -1},
    {0, 0, -1}, {1, 0, -1}, {-1, -1, -1}, {0, -1, -1}, {1, -1, -1}};

// Module-owned scratch (d_ws unused). Everything read is rewritten each call.
__device__ float4 cla_pp[CLA_NATOMS];      // wrapped coords
__device__ float4 cla_sorted[CLA_NATOMS];  // bin-sorted coords, .w = original i
__device__ unsigned cla_hist[CLA_NCELL];
__device__ unsigned cla_cstart[CLA_NCELL + 1];
__device__ unsigned cla_cfill[CLA_NCELL];
__device__ int cla_jbuf[(size_t)CLA_NROWS * CLA_CAP];  // per-row sorted hit j's
__device__ unsigned cla_cnt[CLA_NROWS];
__device__ unsigned cla_off[CLA_NROWS];
__device__ unsigned cla_tot[CLA_NTILE];
__device__ float4 cla_dg;              // cell diagonal
__device__ float4 cla_cinv;            // 8/diag per axis
__device__ float4 cla_sf[CLA_NSHIFT];  // s * diag (f32, __fmul_rn)

// --- setup: f64 constant math once + zero the bin histogram ----------------
__global__ __launch_bounds__(512) void cla_setup(const float* __restrict__ cell) {
  int t = threadIdx.x;
  if (t < CLA_NCELL) cla_hist[t] = 0u;
  if (t == 0) {
    float dgx = (float)sqrt((double)cell[0] * cell[0] + (double)cell[3] * cell[3] +
                            (double)cell[6] * cell[6]);
    float dgy = (float)sqrt((double)cell[1] * cell[1] + (double)cell[4] * cell[4] +
                            (double)cell[7] * cell[7]);
    float dgz = (float)sqrt((double)cell[2] * cell[2] + (double)cell[5] * cell[5] +
                            (double)cell[8] * cell[8]);
    cla_dg = make_float4(dgx, dgy, dgz, 0.f);
    cla_cinv = make_float4(8.0f / dgx, 8.0f / dgy, 8.0f / dgz, 0.f);
    for (int k = 0; k < CLA_NSHIFT; ++k)
      cla_sf[k] = make_float4(__fmul_rn((float)cla_shifts[k][0], dgx),
                              __fmul_rn((float)cla_shifts[k][1], dgy),
                              __fmul_rn((float)cla_shifts[k][2], dgz), 0.f);
  }
}

__device__ __forceinline__ int cla_cellof(const float4& p, const float4& cinv) {
  int cx = min(7, (int)(p.x * cinv.x));
  int cy = min(7, (int)(p.y * cinv.y));
  int cz = min(7, (int)(p.z * cinv.z));
  return (cz * 8 + cy) * 8 + cx;  // x fastest -> contiguous x-runs
}

// --- wrap + bin fused: each thread wraps its atom, then histograms it -------
__global__ __launch_bounds__(256) void cla_wrapbin(const float* __restrict__ coords,
                                                   const float* __restrict__ cell) {
  int i = blockIdx.x * blockDim.x + threadIdx.x;
  if (i >= CLA_NATOMS) return;
  double a00 = cell[0], a01 = cell[1], a02 = cell[2];
  double a10 = cell[3], a11 = cell[4], a12 = cell[5];
  double a20 = cell[6], a21 = cell[7], a22 = cell[8];
  double det = a00 * (a11 * a22 - a12 * a21) - a01 * (a10 * a22 - a12 * a20) +
               a02 * (a10 * a21 - a11 * a20);
  double id = 1.0 / det;
  float inv[3][3];
  inv[0][0] = (float)((a11 * a22 - a12 * a21) * id);
  inv[0][1] = (float)(-(a01 * a22 - a02 * a21) * id);
  inv[0][2] = (float)((a01 * a12 - a02 * a11) * id);
  inv[1][0] = (float)(-(a10 * a22 - a12 * a20) * id);
  inv[1][1] = (float)((a00 * a22 - a02 * a20) * id);
  inv[1][2] = (float)(-(a00 * a12 - a02 * a10) * id);
  inv[2][0] = (float)((a10 * a21 - a11 * a20) * id);
  inv[2][1] = (float)(-(a00 * a21 - a01 * a20) * id);
  inv[2][2] = (float)((a00 * a11 - a01 * a10) * id);

  float x = coords[3 * i], y = coords[3 * i + 1], z = coords[3 * i + 2];
  float fr[3], w[3];
#pragma unroll
  for (int c = 0; c < 3; ++c) {
    float f = __fadd_rn(__fadd_rn(__fmul_rn(x, inv[0][c]), __fmul_rn(y, inv[1][c])),
                        __fmul_rn(z, inv[2][c]));
    fr[c] = __fsub_rn(f, floorf(f));
  }
#pragma unroll
  for (int c = 0; c < 3; ++c) {
    w[c] = __fadd_rn(
        __fadd_rn(__fmul_rn(fr[0], cell[0 * 3 + c]), __fmul_rn(fr[1], cell[1 * 3 + c])),
        __fmul_rn(fr[2], cell[2 * 3 + c]));
  }
  float4 p = make_float4(w[0], w[1], w[2], 0.0f);
  cla_pp[i] = p;
  atomicAdd(&cla_hist[cla_cellof(p, cla_cinv)], 1u);
}

// --- cscan: exclusive scan of 512 cell counts -------------------------------
__global__ __launch_bounds__(512) void cla_cscan() {
  __shared__ unsigned sd[512];
  int t = threadIdx.x;
  unsigned v = cla_hist[t];
  sd[t] = v;
  __syncthreads();
  unsigned acc = v;
  for (int off = 1; off < 512; off <<= 1) {
    unsigned a = (t >= off) ? sd[t - off] : 0u;
    __syncthreads();
    acc += a;
    sd[t] = acc;
    __syncthreads();
  }
  cla_cstart[t] = acc - v;
  cla_cfill[t] = acc - v;
  if (t == 511) cla_cstart[512] = acc;
}

// --- scatter: bin-sort atoms (intra-cell order nondeterministic; output-
// invariant since hits become bits keyed by original index) ------------------
__global__ __launch_bounds__(256) void cla_scatter() {
  int i = blockIdx.x * blockDim.x + threadIdx.x;
  if (i >= CLA_NATOMS) return;
  float4 p = cla_pp[i];
  int c = cla_cellof(p, cla_cinv);
  unsigned pos = atomicAdd(&cla_cfill[c], 1u);
  p.w = __int_as_float(i);
  cla_sorted[pos] = p;
}

// Slab prune: d2<=c2 forces shifted atom i into a cutoff-wide boundary slab.
__device__ __forceinline__ bool cla_alive(float xi, float yi, float zi, int sx, int sy,
                                          int sz, float dgx, float dgy, float dgz) {
  bool a = true;
  if (sx < 0) a = a && (xi >= dgx - 5.3f); else if (sx > 0) a = a && (xi <= 5.3f);
  if (sy < 0) a = a && (yi >= dgy - 5.3f); else if (sy > 0) a = a && (yi <= 5.3f);
  if (sz < 0) a = a && (zi >= dgz - 5.3f); else if (sz > 0) a = a && (zi <= 5.3f);
  return a;
}

// Candidate cell range on one axis (monotone-rounding safe, 0.14 slack).
__device__ __forceinline__ void cla_crange(float t, float ci, int& lo, int& hi) {
  lo = max(0, (int)(fmaxf(t - CLA_R, 0.f) * ci));
  hi = min(7, (int)(fmaxf(t + CLA_R, 0.f) * ci));
}

__device__ __forceinline__ unsigned cla_iscan(unsigned v, int lane) {
  for (int off = 1; off < 64; off <<= 1) {
    unsigned t = __shfl_up(v, off);
    if (lane >= off) v += t;
  }
  return v;
}

// --- count: one wave per (k,i) row; test cell-list candidates into an LDS
// bitmask, then expand in-wave to a SORTED compact j-list + row count --------
__global__ __launch_bounds__(512) void cla_count() {
  __shared__ uint4 smask[8][64];  // 1KB mask per wave
  int wslot = threadIdx.x >> 6;
  int wv = blockIdx.x * 8 + wslot;
  int lane = threadIdx.x & 63;
  unsigned* lm = (unsigned*)smask[wslot];
  int k = wv >> 13, i = wv & (CLA_NATOMS - 1);

  float4 dg = cla_dg;
  float4 sc = cla_sf[k];
  int sx = cla_shifts[k][0], sy = cla_shifts[k][1], sz = cla_shifts[k][2];
  float4 pi = cla_pp[i];
  if (k != 0 && !cla_alive(pi.x, pi.y, pi.z, sx, sy, sz, dg.x, dg.y, dg.z)) {
    if (lane == 0) cla_cnt[wv] = 0u;
    return;
  }
  smask[wslot][lane] = make_uint4(0u, 0u, 0u, 0u);

  float4 cinv = cla_cinv;
  int xlo, xhi, ylo, yhi, zlo, zhi;
  cla_crange(__fadd_rn(pi.x, sc.x), cinv.x, xlo, xhi);
  cla_crange(__fadd_rn(pi.y, sc.y), cinv.y, ylo, yhi);
  cla_crange(__fadd_rn(pi.z, sc.z), cinv.z, zlo, zhi);

  for (int cz = zlo; cz <= zhi; ++cz) {
    for (int cy = ylo; cy <= yhi; ++cy) {
      int idb = (cz * 8 + cy) * 8;
      unsigned b = cla_cstart[idb + xlo], e = cla_cstart[idb + xhi + 1];
      for (unsigned t = b + lane; t < e; t += 64) {
        float4 pj = cla_sorted[t];
        int j = __float_as_int(pj.w);
        float dx = __fadd_rn(__fsub_rn(pi.x, pj.x), sc.x);
        float dy = __fadd_rn(__fsub_rn(pi.y, pj.y), sc.y);
        float dz = __fadd_rn(__fsub_rn(pi.z, pj.z), sc.z);
        float d2 = __fadd_rn(__fadd_rn(__fmul_rn(dx, dx), __fmul_rn(dy, dy)),
                             __fmul_rn(dz, dz));
        bool ok = (d2 <= CLA_C2) && (k != 0 || i < j);
        if (ok) atomicOr(&lm[(unsigned)j >> 5], 1u << (j & 31));
      }
    }
  }
  __threadfence_block();  // drain LDS atomics before cross-lane mask read

  const unsigned long long* mrow = (const unsigned long long*)lm;
  unsigned long long m0 = mrow[lane];       // j in [64*lane, 64*lane+64)
  unsigned long long m1 = mrow[64 + lane];  // j in [4096+64*lane, ...)
  unsigned c0 = (unsigned)__popcll(m0), c1 = (unsigned)__popcll(m1);
  unsigned s0 = cla_iscan(c0, lane);
  unsigned T0 = __shfl(s0, 63);
  unsigned e0 = s0 - c0;
  unsigned s1 = cla_iscan(c1, lane);
  unsigned T1 = __shfl(s1, 63);
  unsigned e1 = T0 + s1 - c1;

  size_t jb = (size_t)wv * CLA_CAP;
  unsigned p = e0;
  unsigned long long m = m0;
  while (m) {
    int b = __ffsll((long long)m) - 1;
    m &= m - 1;
    if (p < CLA_CAP) cla_jbuf[jb + p] = (lane << 6) + b;
    ++p;
  }
  p = e1;
  m = m1;
  while (m) {
    int b = __ffsll((long long)m) - 1;
    m &= m - 1;
    if (p < CLA_CAP) cla_jbuf[jb + p] = ((64 + lane) << 6) + b;
    ++p;
  }
  if (lane == 0) cla_cnt[wv] = min(T0 + T1, (unsigned)CLA_CAP);
}

// --- scan stage 1: per-1024-row tile exclusive scan + tile total ------------
__global__ __launch_bounds__(1024) void cla_s1() {
  __shared__ unsigned sd[1024];
  int t = threadIdx.x;
  int gid = blockIdx.x * 1024 + t;
  unsigned v = cla_cnt[gid];
  sd[t] = v;
  __syncthreads();
  unsigned acc = v;
  for (int off = 1; off < 1024; off <<= 1) {
    unsigned a = (t >= off) ? sd[t - off] : 0u;
    __syncthreads();
    acc += a;
    sd[t] = acc;
    __syncthreads();
  }
  cla_off[gid] = acc - v;
  if (t == 1023) cla_tot[blockIdx.x] = acc;
}

// --- scan stage 2 + emit fused: add tile base, then each thread writes its
// row's pairs straight into [ i xP | j xP | (sx,sy,sz) xP ] ------------------
__global__ __launch_bounds__(1024) void cla_s2emit(int* __restrict__ out, int P) {
  __shared__ unsigned sred[16];
  int t = threadIdx.x;
  unsigned v = (t < blockIdx.x) ? cla_tot[t] : 0u;  // blockIdx.x <= 111 < 1024
#pragma unroll
  for (int off = 32; off; off >>= 1) v += __shfl_down(v, off);
  if ((t & 63) == 0) sred[t >> 6] = v;
  __syncthreads();
  if (t == 0) {
    unsigned b = 0;
#pragma unroll
    for (int w = 0; w < 16; ++w) b += sred[w];
    sred[0] = b;
  }
  __syncthreads();

  int row = blockIdx.x * 1024 + t;
  unsigned c = cla_cnt[row];
  if (c == 0) return;
  unsigned off = cla_off[row] + sred[0];
  int i = row & (CLA_NATOMS - 1), k = row >> 13;
  int sx = cla_shifts[k][0], sy = cla_shifts[k][1], sz = cla_shifts[k][2];
  size_t jb = (size_t)row * CLA_CAP;
  for (unsigned q = 0; q < c; ++q) {
    unsigned p = off + q;
    if (p < (unsigned)P) {
      out[p] = i;
      out[P + p] = cla_jbuf[jb + q];
      unsigned sp = 2u * (unsigned)P + 3u * p;
      out[sp] = sx;
      out[sp + 1] = sy;
      out[sp + 2] = sz;
    }
  }
}

extern "C" void kernel_launch(void* const* d_in, const int* in_sizes, int n_in,
                              void* d_out, int out_size, void* d_ws, size_t ws_size,
                              hipStream_t stream) {
  const float* coords = (const float*)d_in[1];  // (1, N, 3) f32
  const float* cell = (const float*)d_in[2];    // (3, 3) f32
  int P = out_size / 5;

  cla_setup<<<1, 512, 0, stream>>>(cell);
  cla_wrapbin<<<CLA_NATOMS / 256, 256, 0, stream>>>(coords, cell);
  cla_cscan<<<1, 512, 0, stream>>>();
  cla_scatter<<<CLA_NATOMS / 256, 256, 0, stream>>>();
  cla_count<<<CLA_NROWS / 8, 512, 0, stream>>>();
  cla_s1<<<CLA_NTILE, 1024, 0, stream>>>();
  cla_s2emit<<<CLA_NTILE, 1024, 0, stream>>>((int*)d_out, P);
}

// Round 11
// 55.663 us; speedup vs baseline: 3.7649x; 3.7649x over previous
//
#include <hip/hip_runtime.h>

#define CLB_NATOMS 8192
#define CLB_NSHIFT 14
#define CLB_NROWS (CLB_NSHIFT * CLB_NATOMS)  // 114688 rows = (k, i)
#define CLB_NTILE 112                        // scan tiles of 1024 rows
#define CLB_NCELL 512                        // 8x8x8 spatial bins
#define CLB_CAP 128                          // max hits per row (k=0 max ~90)
#define CLB_C2 ((float)(5.2 * 5.2))          // f32 compare (JAX weak promotion)
#define CLB_R 5.35f                          // candidate interval half-width

__device__ const int clb_shifts[CLB_NSHIFT][3] = {
    {0, 0, 0},
    {-1, 0, 0}, {-1, -1, 0}, {0, -1, 0}, {1, -1, 0},
    {-1, 1, -1}, {0, 1, -1}, {1, 1, -1}, {-1, 0, -1},
    {0, 0, -1}, {1, 0, -1}, {-1, -1, -1}, {0, -1, -1}, {1, -1, -1}};

// Module-owned scratch (d_ws unused). Everything read is rewritten each call.
__device__ float4 clb_pp[CLB_NATOMS];      // wrapped coords
__device__ float4 clb_sorted[CLB_NATOMS];  // bin-sorted coords, .w = original i
__device__ unsigned clb_hist[CLB_NCELL];
__device__ unsigned clb_cstart[CLB_NCELL + 1];
__device__ unsigned clb_cfill[CLB_NCELL];
__device__ int clb_jbuf[(size_t)CLB_NROWS * CLB_CAP];  // per-row sorted hit j's
__device__ unsigned clb_cnt[CLB_NROWS];
__device__ unsigned clb_off[CLB_NROWS];
__device__ unsigned clb_tot[CLB_NTILE];
__device__ float4 clb_dg;              // cell diagonal
__device__ float4 clb_cinv;            // 8/diag per axis
__device__ float4 clb_sf[CLB_NSHIFT];  // s * diag (f32, __fmul_rn)

// --- setup: f64 constant math once + zero the bin histogram ----------------
__global__ __launch_bounds__(512) void clb_setup(const float* __restrict__ cell) {
  int t = threadIdx.x;
  if (t < CLB_NCELL) clb_hist[t] = 0u;
  if (t == 0) {
    float dgx = (float)sqrt((double)cell[0] * cell[0] + (double)cell[3] * cell[3] +
                            (double)cell[6] * cell[6]);
    float dgy = (float)sqrt((double)cell[1] * cell[1] + (double)cell[4] * cell[4] +
                            (double)cell[7] * cell[7]);
    float dgz = (float)sqrt((double)cell[2] * cell[2] + (double)cell[5] * cell[5] +
                            (double)cell[8] * cell[8]);
    clb_dg = make_float4(dgx, dgy, dgz, 0.f);
    clb_cinv = make_float4(8.0f / dgx, 8.0f / dgy, 8.0f / dgz, 0.f);
    for (int k = 0; k < CLB_NSHIFT; ++k)
      clb_sf[k] = make_float4(__fmul_rn((float)clb_shifts[k][0], dgx),
                              __fmul_rn((float)clb_shifts[k][1], dgy),
                              __fmul_rn((float)clb_shifts[k][2], dgz), 0.f);
  }
}

__device__ __forceinline__ int clb_cellof(const float4& p, const float4& cinv) {
  int cx = min(7, (int)(p.x * cinv.x));
  int cy = min(7, (int)(p.y * cinv.y));
  int cz = min(7, (int)(p.z * cinv.z));
  return (cz * 8 + cy) * 8 + cx;  // x fastest -> contiguous x-runs
}

// --- wrap + bin fused: each thread wraps its atom, then histograms it -------
__global__ __launch_bounds__(256) void clb_wrapbin(const float* __restrict__ coords,
                                                   const float* __restrict__ cell) {
  int i = blockIdx.x * blockDim.x + threadIdx.x;
  if (i >= CLB_NATOMS) return;
  double a00 = cell[0], a01 = cell[1], a02 = cell[2];
  double a10 = cell[3], a11 = cell[4], a12 = cell[5];
  double a20 = cell[6], a21 = cell[7], a22 = cell[8];
  double det = a00 * (a11 * a22 - a12 * a21) - a01 * (a10 * a22 - a12 * a20) +
               a02 * (a10 * a21 - a11 * a20);
  double id = 1.0 / det;
  float inv[3][3];
  inv[0][0] = (float)((a11 * a22 - a12 * a21) * id);
  inv[0][1] = (float)(-(a01 * a22 - a02 * a21) * id);
  inv[0][2] = (float)((a01 * a12 - a02 * a11) * id);
  inv[1][0] = (float)(-(a10 * a22 - a12 * a20) * id);
  inv[1][1] = (float)((a00 * a22 - a02 * a20) * id);
  inv[1][2] = (float)(-(a00 * a12 - a02 * a10) * id);
  inv[2][0] = (float)((a10 * a21 - a11 * a20) * id);
  inv[2][1] = (float)(-(a00 * a21 - a01 * a20) * id);
  inv[2][2] = (float)((a00 * a11 - a01 * a10) * id);

  float x = coords[3 * i], y = coords[3 * i + 1], z = coords[3 * i + 2];
  float fr[3], w[3];
#pragma unroll
  for (int c = 0; c < 3; ++c) {
    float f = __fadd_rn(__fadd_rn(__fmul_rn(x, inv[0][c]), __fmul_rn(y, inv[1][c])),
                        __fmul_rn(z, inv[2][c]));
    fr[c] = __fsub_rn(f, floorf(f));
  }
#pragma unroll
  for (int c = 0; c < 3; ++c) {
    w[c] = __fadd_rn(
        __fadd_rn(__fmul_rn(fr[0], cell[0 * 3 + c]), __fmul_rn(fr[1], cell[1 * 3 + c])),
        __fmul_rn(fr[2], cell[2 * 3 + c]));
  }
  float4 p = make_float4(w[0], w[1], w[2], 0.0f);
  clb_pp[i] = p;
  atomicAdd(&clb_hist[clb_cellof(p, clb_cinv)], 1u);
}

// --- cscan: exclusive scan of 512 cell counts -------------------------------
__global__ __launch_bounds__(512) void clb_cscan() {
  __shared__ unsigned sd[512];
  int t = threadIdx.x;
  unsigned v = clb_hist[t];
  sd[t] = v;
  __syncthreads();
  unsigned acc = v;
  for (int off = 1; off < 512; off <<= 1) {
    unsigned a = (t >= off) ? sd[t - off] : 0u;
    __syncthreads();
    acc += a;
    sd[t] = acc;
    __syncthreads();
  }
  clb_cstart[t] = acc - v;
  clb_cfill[t] = acc - v;
  if (t == 511) clb_cstart[512] = acc;
}

// --- scatter: bin-sort atoms (intra-cell order nondeterministic; output-
// invariant since hits become bits keyed by original index) ------------------
__global__ __launch_bounds__(256) void clb_scatter() {
  int i = blockIdx.x * blockDim.x + threadIdx.x;
  if (i >= CLB_NATOMS) return;
  float4 p = clb_pp[i];
  int c = clb_cellof(p, clb_cinv);
  unsigned pos = atomicAdd(&clb_cfill[c], 1u);
  p.w = __int_as_float(i);
  clb_sorted[pos] = p;
}

// Slab prune: d2<=c2 forces shifted atom i into a cutoff-wide boundary slab.
__device__ __forceinline__ bool clb_alive(float xi, float yi, float zi, int sx, int sy,
                                          int sz, float dgx, float dgy, float dgz) {
  bool a = true;
  if (sx < 0) a = a && (xi >= dgx - 5.3f); else if (sx > 0) a = a && (xi <= 5.3f);
  if (sy < 0) a = a && (yi >= dgy - 5.3f); else if (sy > 0) a = a && (yi <= 5.3f);
  if (sz < 0) a = a && (zi >= dgz - 5.3f); else if (sz > 0) a = a && (zi <= 5.3f);
  return a;
}

// Candidate cell range on one axis (monotone-rounding safe, 0.14 slack).
__device__ __forceinline__ void clb_crange(float t, float ci, int& lo, int& hi) {
  lo = max(0, (int)(fmaxf(t - CLB_R, 0.f) * ci));
  hi = min(7, (int)(fmaxf(t + CLB_R, 0.f) * ci));
}

__device__ __forceinline__ unsigned clb_iscan(unsigned v, int lane) {
  for (int off = 1; off < 64; off <<= 1) {
    unsigned t = __shfl_up(v, off);
    if (lane >= off) v += t;
  }
  return v;
}

// --- count: one wave per (k,i) row; test cell-list candidates into an LDS
// bitmask, then expand in-wave to a SORTED compact j-list + row count --------
__global__ __launch_bounds__(512) void clb_count() {
  __shared__ uint4 smask[8][64];  // 1KB mask per wave
  int wslot = threadIdx.x >> 6;
  int wv = blockIdx.x * 8 + wslot;
  int lane = threadIdx.x & 63;
  unsigned* lm = (unsigned*)smask[wslot];
  int k = wv >> 13, i = wv & (CLB_NATOMS - 1);

  float4 dg = clb_dg;
  float4 sc = clb_sf[k];
  int sx = clb_shifts[k][0], sy = clb_shifts[k][1], sz = clb_shifts[k][2];
  float4 pi = clb_pp[i];
  if (k != 0 && !clb_alive(pi.x, pi.y, pi.z, sx, sy, sz, dg.x, dg.y, dg.z)) {
    if (lane == 0) clb_cnt[wv] = 0u;
    return;
  }
  smask[wslot][lane] = make_uint4(0u, 0u, 0u, 0u);

  float4 cinv = clb_cinv;
  int xlo, xhi, ylo, yhi, zlo, zhi;
  clb_crange(__fadd_rn(pi.x, sc.x), cinv.x, xlo, xhi);
  clb_crange(__fadd_rn(pi.y, sc.y), cinv.y, ylo, yhi);
  clb_crange(__fadd_rn(pi.z, sc.z), cinv.z, zlo, zhi);

  for (int cz = zlo; cz <= zhi; ++cz) {
    for (int cy = ylo; cy <= yhi; ++cy) {
      int idb = (cz * 8 + cy) * 8;
      unsigned b = clb_cstart[idb + xlo], e = clb_cstart[idb + xhi + 1];
      for (unsigned t = b + lane; t < e; t += 64) {
        float4 pj = clb_sorted[t];
        int j = __float_as_int(pj.w);
        float dx = __fadd_rn(__fsub_rn(pi.x, pj.x), sc.x);
        float dy = __fadd_rn(__fsub_rn(pi.y, pj.y), sc.y);
        float dz = __fadd_rn(__fsub_rn(pi.z, pj.z), sc.z);
        float d2 = __fadd_rn(__fadd_rn(__fmul_rn(dx, dx), __fmul_rn(dy, dy)),
                             __fmul_rn(dz, dz));
        bool ok = (d2 <= CLB_C2) && (k != 0 || i < j);
        if (ok) atomicOr(&lm[(unsigned)j >> 5], 1u << (j & 31));
      }
    }
  }
  __threadfence_block();  // drain LDS atomics before cross-lane mask read

  const unsigned long long* mrow = (const unsigned long long*)lm;
  unsigned long long m0 = mrow[lane];       // j in [64*lane, 64*lane+64)
  unsigned long long m1 = mrow[64 + lane];  // j in [4096+64*lane, ...)
  unsigned c0 = (unsigned)__popcll(m0), c1 = (unsigned)__popcll(m1);
  unsigned s0 = clb_iscan(c0, lane);
  unsigned T0 = __shfl(s0, 63);
  unsigned e0 = s0 - c0;
  unsigned s1 = clb_iscan(c1, lane);
  unsigned T1 = __shfl(s1, 63);
  unsigned e1 = T0 + s1 - c1;

  size_t jb = (size_t)wv * CLB_CAP;
  unsigned p = e0;
  unsigned long long m = m0;
  while (m) {
    int b = __ffsll((long long)m) - 1;
    m &= m - 1;
    if (p < CLB_CAP) clb_jbuf[jb + p] = (lane << 6) + b;
    ++p;
  }
  p = e1;
  m = m1;
  while (m) {
    int b = __ffsll((long long)m) - 1;
    m &= m - 1;
    if (p < CLB_CAP) clb_jbuf[jb + p] = ((64 + lane) << 6) + b;
    ++p;
  }
  if (lane == 0) clb_cnt[wv] = min(T0 + T1, (unsigned)CLB_CAP);
}

// --- scan stage 1: per-1024-row tile exclusive scan + tile total ------------
__global__ __launch_bounds__(1024) void clb_s1() {
  __shared__ unsigned sd[1024];
  int t = threadIdx.x;
  int gid = blockIdx.x * 1024 + t;
  unsigned v = clb_cnt[gid];
  sd[t] = v;
  __syncthreads();
  unsigned acc = v;
  for (int off = 1; off < 1024; off <<= 1) {
    unsigned a = (t >= off) ? sd[t - off] : 0u;
    __syncthreads();
    acc += a;
    sd[t] = acc;
    __syncthreads();
  }
  clb_off[gid] = acc - v;
  if (t == 1023) clb_tot[blockIdx.x] = acc;
}

// --- scan stage 2: add sum of preceding tile totals to row offsets ----------
__global__ __launch_bounds__(1024) void clb_s2() {
  __shared__ unsigned sred[16];
  int t = threadIdx.x;
  unsigned v = (t < blockIdx.x) ? clb_tot[t] : 0u;  // blockIdx.x <= 111 < 1024
#pragma unroll
  for (int off = 32; off; off >>= 1) v += __shfl_down(v, off);
  if ((t & 63) == 0) sred[t >> 6] = v;
  __syncthreads();
  if (t == 0) {
    unsigned b = 0;
#pragma unroll
    for (int w = 0; w < 16; ++w) b += sred[w];
    sred[0] = b;
  }
  __syncthreads();
  clb_off[blockIdx.x * 1024 + t] += sred[0];
}

// --- emit: one wave per row; lanes copy the row's compact j-list into the
// int32 stream [ i xP | j xP | (sx,sy,sz) xP ] with coalesced writes ---------
__global__ __launch_bounds__(512) void clb_emit(int* __restrict__ out, int P) {
  int wv = blockIdx.x * 8 + (threadIdx.x >> 6);
  int lane = threadIdx.x & 63;
  unsigned c = clb_cnt[wv];
  if (c == 0) return;
  unsigned off = clb_off[wv];
  int k = wv >> 13, i = wv & (CLB_NATOMS - 1);
  int sx = clb_shifts[k][0], sy = clb_shifts[k][1], sz = clb_shifts[k][2];
  size_t jb = (size_t)wv * CLB_CAP;
  for (unsigned q = lane; q < c; q += 64) {
    unsigned p = off + q;
    if (p < (unsigned)P) {
      out[p] = i;
      out[P + p] = clb_jbuf[jb + q];
      unsigned sp = 2u * (unsigned)P + 3u * p;
      out[sp] = sx;
      out[sp + 1] = sy;
      out[sp + 2] = sz;
    }
  }
}

extern "C" void kernel_launch(void* const* d_in, const int* in_sizes, int n_in,
                              void* d_out, int out_size, void* d_ws, size_t ws_size,
                              hipStream_t stream) {
  const float* coords = (const float*)d_in[1];  // (1, N, 3) f32
  const float* cell = (const float*)d_in[2];    // (3, 3) f32
  int P = out_size / 5;

  clb_setup<<<1, 512, 0, stream>>>(cell);
  clb_wrapbin<<<CLB_NATOMS / 256, 256, 0, stream>>>(coords, cell);
  clb_cscan<<<1, 512, 0, stream>>>();
  clb_scatter<<<CLB_NATOMS / 256, 256, 0, stream>>>();
  clb_count<<<CLB_NROWS / 8, 512, 0, stream>>>();
  clb_s1<<<CLB_NTILE, 1024, 0, stream>>>();
  clb_s2<<<CLB_NTILE, 1024, 0, stream>>>();
  clb_emit<<<CLB_NROWS / 8, 512, 0, stream>>>((int*)d_out, P);
}